// Round 2
// baseline (1001.715 us; speedup 1.0000x reference)
//
#include <hip/hip_runtime.h>
#include <hip/hip_bf16.h>
#include <math.h>

#define DIM 1024
#define BATCH 16384
#define NLAYER 6

typedef __bf16 bf16_t;
typedef __attribute__((ext_vector_type(8))) __bf16 bf16x8;
typedef __attribute__((ext_vector_type(4))) float f32x4;

__device__ __forceinline__ void gload16(const void* g, void* l) {
  __builtin_amdgcn_global_load_lds(
      (const __attribute__((address_space(1))) void*)g,
      (__attribute__((address_space(3))) void*)l, 16, 0, 0);
}

__device__ __forceinline__ float fast_tanh(float x) {
  x = fminf(9.f, fmaxf(-9.f, x));
  const float e = __expf(x + x);
  return (e - 1.f) * __builtin_amdgcn_rcpf(e + 1.f);
}

__device__ __forceinline__ float bf2f(unsigned short u) {
  return __uint_as_float(((unsigned int)u) << 16);
}

// ---------------------------------------------------------------------------
// GEMM: C[m,n] = sum_k A[m,k] * W[n,k]  (A [BATCH x DIM] bf16, W [DIM x DIM] bf16)
// MODE 0: Tb = bf16( fast_tanh(scale[m]*C + b1[n]) )
// MODE 1: hb[m,n] = coef.w*hb_old + C + b2[n] + ce*e[n] + cc*c[n] + cn*nn[n]
// MODE 2: MODE1 + also write fp32 result to outF (final layer)
// 128x128 tile, BK=64, 4 waves (2x2), 4x4 of 16x16x32 MFMA.
// LDS XOR swizzle: phys_chunk = logical_chunk ^ (row & 7)  (chunk = 16B)
// ---------------------------------------------------------------------------
template <int MODE>
__global__ __launch_bounds__(256) void gemm_kernel(
    const bf16_t* __restrict__ A, const bf16_t* __restrict__ W,
    const float* __restrict__ bias, bf16_t* __restrict__ outB,
    float* __restrict__ outF, const f32x4* __restrict__ coef,
    const float* __restrict__ dirs, const float* __restrict__ scaleArr,
    const bf16_t* __restrict__ hbIn) {
  __shared__ __align__(16) bf16_t sA[128 * 64];
  __shared__ __align__(16) bf16_t sB[128 * 64];
  const int tid = threadIdx.x;
  const int w = tid >> 6;
  const int lane = tid & 63;
  const int bm = blockIdx.x * 128;
  const int bn = blockIdx.y * 128;
  const int wm = (w & 1) * 64;
  const int wn = (w >> 1) * 64;
  const int lm = lane & 15;
  const int lc = lane >> 4;  // 0..3

  f32x4 acc[4][4] = {};

  // staging: thread -> (row group srow = tid>>3, phys chunk p = tid&7)
  // content at (row, p) must be logical chunk p ^ (row&7); row&7 == srow&7.
  const int srow = tid >> 3;
  const int swz = ((tid & 7) ^ (srow & 7)) * 8;  // element offset in row
  const bf16_t* gA = A + (size_t)(bm + srow) * DIM + swz;
  const bf16_t* gW = W + (size_t)(bn + srow) * DIM + swz;
  // wave-uniform LDS bases; round q covers rows q*32..q*32+31
  char* lA = (char*)sA + w * 1024;
  char* lB = (char*)sB + w * 1024;

  for (int kt = 0; kt < DIM; kt += 64) {
#pragma unroll
    for (int q = 0; q < 4; ++q) {
      gload16(gA + kt + (size_t)q * 32 * DIM, lA + q * 4096);
      gload16(gW + kt + (size_t)q * 32 * DIM, lB + q * 4096);
    }
    __syncthreads();  // drain staging
#pragma unroll
    for (int kh = 0; kh < 2; ++kh) {
      bf16x8 aF[4], bF[4];
      const int lgc = kh * 4 + lc;  // logical 16B chunk within row
#pragma unroll
      for (int i = 0; i < 4; ++i) {
        const int rowA = wm + i * 16 + lm;
        aF[i] = *(const bf16x8*)((char*)sA + rowA * 128 +
                                 ((lgc ^ (lm & 7)) << 4));
      }
#pragma unroll
      for (int j = 0; j < 4; ++j) {
        const int rowB = wn + j * 16 + lm;
        bF[j] = *(const bf16x8*)((char*)sB + rowB * 128 +
                                 ((lgc ^ (lm & 7)) << 4));
      }
#pragma unroll
      for (int i = 0; i < 4; ++i)
#pragma unroll
        for (int j = 0; j < 4; ++j)
          acc[i][j] = __builtin_amdgcn_mfma_f32_16x16x32_bf16(
              aF[i], bF[j], acc[i][j], 0, 0, 0);
    }
    __syncthreads();  // protect LDS before next stage
  }

  // C/D layout: col = lane&15, row = (lane>>4)*4 + reg  [m89/m91]
  const int r0 = lc << 2;
#pragma unroll
  for (int i = 0; i < 4; ++i) {
    const int rowBase = bm + wm + i * 16 + r0;
    if constexpr (MODE == 0) {
      float s4[4];
#pragma unroll
      for (int r = 0; r < 4; ++r) s4[r] = scaleArr[rowBase + r];
#pragma unroll
      for (int j = 0; j < 4; ++j) {
        const int col = bn + wn + j * 16 + lm;
        const float bv = bias[col];
#pragma unroll
        for (int r = 0; r < 4; ++r)
          outB[(size_t)(rowBase + r) * DIM + col] =
              (bf16_t)fast_tanh(s4[r] * acc[i][j][r] + bv);
      }
    } else {
      f32x4 cf[4];
#pragma unroll
      for (int r = 0; r < 4; ++r) cf[r] = coef[rowBase + r];
#pragma unroll
      for (int j = 0; j < 4; ++j) {
        const int col = bn + wn + j * 16 + lm;
        const float base = bias[col] + cf[0].x * 0.f;  // keep order simple
        const float ev = dirs[col];
        const float cv = dirs[DIM + col];
        const float nv = dirs[2 * DIM + col];
#pragma unroll
        for (int r = 0; r < 4; ++r) {
          const size_t idx = (size_t)(rowBase + r) * DIM + col;
          const float hp = (float)hbIn[idx];
          const float v = acc[i][j][r] + base + cf[r].x * ev + cf[r].y * cv +
                          cf[r].z * nv + cf[r].w * hp;
          outB[idx] = (bf16_t)v;
          if constexpr (MODE == 2) outF[idx] = v;
        }
      }
    }
  }
}

// ---------------------------------------------------------------------------
// Per-row stats: reduce ||h||^2 and dots with e/c/n; produce
//   scaleArr[row] = clamp scale (1 or 10/(norm+1e-8))
//   coef[row] = {ce, cc, cn, fac= scale*(1-ce-cc-cn)}
// with ce = S_E*(1-a_e)/||h_c - e|| etc., ||h_c-d||^2 = nc^2 - 2*nc*a + 1.
// IN_FP32: src is fp32 (layer 0, also writes hb). Else src is bf16.
// ---------------------------------------------------------------------------
template <int IN_FP32>
__global__ __launch_bounds__(256) void stats_kernel(
    const void* __restrict__ src, bf16_t* __restrict__ dstb,
    float* __restrict__ scaleArr, f32x4* __restrict__ coef,
    const float* __restrict__ dirs, int doClamp) {
  const int row = blockIdx.x;
  const int t = threadIdx.x;
  float4 v;
  if constexpr (IN_FP32) {
    v = ((const float4*)src)[(size_t)row * 256 + t];
  } else {
    const ushort4 u = ((const ushort4*)src)[(size_t)row * 256 + t];
    v.x = bf2f(u.x); v.y = bf2f(u.y); v.z = bf2f(u.z); v.w = bf2f(u.w);
  }
  const float4 e = ((const float4*)dirs)[t];
  const float4 c = ((const float4*)dirs)[t + 256];
  const float4 n = ((const float4*)dirs)[t + 512];
  float ss = v.x * v.x + v.y * v.y + v.z * v.z + v.w * v.w;
  float de = v.x * e.x + v.y * e.y + v.z * e.z + v.w * e.w;
  float dc = v.x * c.x + v.y * c.y + v.z * c.z + v.w * c.w;
  float dn = v.x * n.x + v.y * n.y + v.z * n.z + v.w * n.w;
#pragma unroll
  for (int off = 32; off; off >>= 1) {
    ss += __shfl_down(ss, off);
    de += __shfl_down(de, off);
    dc += __shfl_down(dc, off);
    dn += __shfl_down(dn, off);
  }
  __shared__ float red[4][4];
  const int w = t >> 6;
  if ((t & 63) == 0) {
    red[w][0] = ss; red[w][1] = de; red[w][2] = dc; red[w][3] = dn;
  }
  __syncthreads();
  if constexpr (IN_FP32) {
    union { bf16_t b[4]; uint2 u; } pk;
    pk.b[0] = (bf16_t)v.x; pk.b[1] = (bf16_t)v.y;
    pk.b[2] = (bf16_t)v.z; pk.b[3] = (bf16_t)v.w;
    ((uint2*)dstb)[(size_t)row * 256 + t] = pk.u;
  }
  if (t == 0) {
    float S = 0, E = 0, C = 0, N = 0;
#pragma unroll
    for (int i = 0; i < 4; ++i) {
      S += red[i][0]; E += red[i][1]; C += red[i][2]; N += red[i][3];
    }
    const float norm = sqrtf(S);
    float scale = 1.f;
    if (doClamp && norm > 10.f) scale = 10.f / (norm + 1e-8f);
    const float invn = 1.f / fmaxf(norm, 1e-12f);
    const float ae = E * invn;  // scale-invariant alignment
    const float ac = C * invn;
    const float an = N * invn;
    const float nc = norm * scale;  // clamped norm
    const float re = sqrtf(fmaxf(nc * nc - 2.f * nc * ae + 1.f, 0.f));
    const float rc = sqrtf(fmaxf(nc * nc - 2.f * nc * ac + 1.f, 0.f));
    const float rn = sqrtf(fmaxf(nc * nc - 2.f * nc * an + 1.f, 0.f));
    const float boundary = fminf(fmaxf(1.f - fabsf(ae - ac), 0.f), 1.f);
    f32x4 cf;
    cf.x = 0.1f * (1.f - ae) / fmaxf(re, 1e-12f);
    cf.y = 0.1f * (1.f - ac) / fmaxf(rc, 1e-12f);
    cf.z = (0.05f * (1.f - an) + 0.05f * boundary) / fmaxf(rn, 1e-12f);
    cf.w = scale * (1.f - cf.x - cf.y - cf.z);
    coef[row] = cf;
    scaleArr[row] = scale;
  }
}

// d_out[row,:] *= scaleArr[row]  (final clamp application, fp32 in-place)
__global__ __launch_bounds__(256) void finalize_kernel(
    float* __restrict__ outF, const float* __restrict__ scaleArr) {
  const int row = blockIdx.x;
  const int t = threadIdx.x;
  const float s = scaleArr[row];
  float4 v = ((float4*)outF)[(size_t)row * 256 + t];
  v.x *= s; v.y *= s; v.z *= s; v.w *= s;
  ((float4*)outF)[(size_t)row * 256 + t] = v;
}

// Normalize the three anchors -> dirs[3*DIM]
__global__ __launch_bounds__(256) void prep_dirs(
    const float* __restrict__ ae, const float* __restrict__ ac,
    const float* __restrict__ an, float* __restrict__ dirs) {
  const int t = threadIdx.x;
  const float4 a = ((const float4*)ae)[t];
  const float4 b = ((const float4*)ac)[t];
  const float4 c = ((const float4*)an)[t];
  float sa = a.x * a.x + a.y * a.y + a.z * a.z + a.w * a.w;
  float sb = b.x * b.x + b.y * b.y + b.z * b.z + b.w * b.w;
  float sc = c.x * c.x + c.y * c.y + c.z * c.z + c.w * c.w;
#pragma unroll
  for (int off = 32; off; off >>= 1) {
    sa += __shfl_down(sa, off);
    sb += __shfl_down(sb, off);
    sc += __shfl_down(sc, off);
  }
  __shared__ float red[4][3];
  __shared__ float fin[3];
  const int w = t >> 6;
  if ((t & 63) == 0) { red[w][0] = sa; red[w][1] = sb; red[w][2] = sc; }
  __syncthreads();
  if (t == 0) {
    float x = 0, y = 0, z = 0;
#pragma unroll
    for (int i = 0; i < 4; ++i) { x += red[i][0]; y += red[i][1]; z += red[i][2]; }
    fin[0] = x; fin[1] = y; fin[2] = z;
  }
  __syncthreads();
  const float ia = 1.f / fmaxf(sqrtf(fin[0]), 1e-12f);
  const float ib = 1.f / fmaxf(sqrtf(fin[1]), 1e-12f);
  const float ic = 1.f / fmaxf(sqrtf(fin[2]), 1e-12f);
  float4 oa, ob, oc;
  oa.x = a.x * ia; oa.y = a.y * ia; oa.z = a.z * ia; oa.w = a.w * ia;
  ob.x = b.x * ib; ob.y = b.y * ib; ob.z = b.z * ib; ob.w = b.w * ib;
  oc.x = c.x * ic; oc.y = c.y * ic; oc.z = c.z * ic; oc.w = c.w * ic;
  ((float4*)dirs)[t] = oa;
  ((float4*)dirs)[t + 256] = ob;
  ((float4*)dirs)[t + 512] = oc;
}

__global__ __launch_bounds__(256) void cast_w_kernel(
    const float* __restrict__ W, bf16_t* __restrict__ Wb) {
  const int i = blockIdx.x * 256 + threadIdx.x;
  const float4 v = ((const float4*)W)[i];
  union { bf16_t b[4]; uint2 u; } pk;
  pk.b[0] = (bf16_t)v.x; pk.b[1] = (bf16_t)v.y;
  pk.b[2] = (bf16_t)v.z; pk.b[3] = (bf16_t)v.w;
  ((uint2*)Wb)[i] = pk.u;
}

extern "C" void kernel_launch(void* const* d_in, const int* in_sizes, int n_in,
                              void* d_out, int out_size, void* d_ws,
                              size_t ws_size, hipStream_t stream) {
  const float* h0 = (const float*)d_in[0];
  const float* W1 = (const float*)d_in[1];
  const float* b1 = (const float*)d_in[2];
  const float* W2 = (const float*)d_in[3];
  const float* b2 = (const float*)d_in[4];
  const float* ae = (const float*)d_in[5];
  const float* ac = (const float*)d_in[6];
  const float* an = (const float*)d_in[7];
  float* outF = (float*)d_out;

  char* ws = (char*)d_ws;
  bf16_t* hb = (bf16_t*)ws;  ws += (size_t)BATCH * DIM * 2;   // 32 MB
  bf16_t* Tb = (bf16_t*)ws;  ws += (size_t)BATCH * DIM * 2;   // 32 MB
  bf16_t* W1b = (bf16_t*)ws; ws += (size_t)DIM * DIM * 2;     // 2 MB
  bf16_t* W2b = (bf16_t*)ws; ws += (size_t)DIM * DIM * 2;     // 2 MB
  float* dirs = (float*)ws;  ws += 3 * DIM * 4;
  f32x4* coef = (f32x4*)ws;  ws += (size_t)BATCH * 16;
  float* scaleArr = (float*)ws; ws += (size_t)BATCH * 4;

  prep_dirs<<<1, 256, 0, stream>>>(ae, ac, an, dirs);
  cast_w_kernel<<<DIM * DIM / 1024, 256, 0, stream>>>(W1, W1b);
  cast_w_kernel<<<DIM * DIM / 1024, 256, 0, stream>>>(W2, W2b);
  // layer-0 stats: no clamp (scale=1), also cast h0 -> hb
  stats_kernel<1><<<BATCH, 256, 0, stream>>>(h0, hb, scaleArr, coef, dirs, 0);

  dim3 grid(BATCH / 128, DIM / 128);
  for (int l = 0; l < NLAYER; ++l) {
    gemm_kernel<0><<<grid, 256, 0, stream>>>(hb, W1b, b1, Tb, nullptr, nullptr,
                                             nullptr, scaleArr, nullptr);
    if (l < NLAYER - 1) {
      gemm_kernel<1><<<grid, 256, 0, stream>>>(Tb, W2b, b2, hb, nullptr, coef,
                                               dirs, nullptr, hb);
      stats_kernel<0><<<BATCH, 256, 0, stream>>>(hb, nullptr, scaleArr, coef,
                                                 dirs, 1);
    } else {
      gemm_kernel<2><<<grid, 256, 0, stream>>>(Tb, W2b, b2, hb, outF, coef,
                                               dirs, nullptr, hb);
      stats_kernel<0><<<BATCH, 256, 0, stream>>>(hb, nullptr, scaleArr, coef,
                                                 dirs, 1);
      finalize_kernel<<<BATCH, 256, 0, stream>>>(outF, scaleArr);
    }
  }
}

// Round 3
// 750.312 us; speedup vs baseline: 1.3351x; 1.3351x over previous
//
#include <hip/hip_runtime.h>
#include <hip/hip_bf16.h>
#include <math.h>

#define DIM 1024
#define BATCH 16384
#define NLAYER 6

typedef __bf16 bf16_t;
typedef __attribute__((ext_vector_type(8))) __bf16 bf16x8;
typedef __attribute__((ext_vector_type(4))) float f32x4;

__device__ __forceinline__ void gload16(const void* g, void* l) {
  __builtin_amdgcn_global_load_lds(
      (const __attribute__((address_space(1))) void*)g,
      (__attribute__((address_space(3))) void*)l, 16, 0, 0);
}

__device__ __forceinline__ float fast_tanh(float x) {
  x = fminf(9.f, fmaxf(-9.f, x));
  const float e = __expf(x + x);
  return (e - 1.f) * __builtin_amdgcn_rcpf(e + 1.f);
}

__device__ __forceinline__ float bf2f(unsigned short u) {
  return __uint_as_float(((unsigned int)u) << 16);
}

// ---------------------------------------------------------------------------
// GEMM: C[m,n] = sum_k A[m,k] * W[n,k]  (A [BATCH x DIM] bf16, W [DIM x DIM] bf16)
// MODE 0: Tb = bf16( fast_tanh(scale[m]*C + b1[n]) )
// MODE 1: hb[m,n] = cf.w*hb_old + C + b2[n] + ce*e[n] + cc*c[n] + cn*nn[n]
// MODE 2: MODE1 + also write fp32 result to outF (final layer)
// 128x128 tile, BK=64, 4 waves (2x2), 4x4 of 16x16x32 MFMA.
// LDS XOR swizzle: phys_chunk = logical_chunk ^ (row & 7)  (chunk = 16B)
// __launch_bounds__(256,4): cap VGPR<=128 so 4 blocks/CU -> grid of 1024
// fully co-resident (R2 regression was 140 VGPR -> 3 blocks/CU + tail).
// ---------------------------------------------------------------------------
template <int MODE>
__global__ __launch_bounds__(256, 4) void gemm_kernel(
    const bf16_t* __restrict__ A, const bf16_t* __restrict__ W,
    const float* __restrict__ bias, bf16_t* __restrict__ outB,
    float* __restrict__ outF, const f32x4* __restrict__ coef,
    const f32x4* __restrict__ colpack, const float* __restrict__ scaleArr,
    const bf16_t* __restrict__ hbIn) {
  __shared__ __align__(16) bf16_t sA[128 * 64];
  __shared__ __align__(16) bf16_t sB[128 * 64];
  const int tid = threadIdx.x;
  const int w = tid >> 6;
  const int lane = tid & 63;
  const int bm = blockIdx.x * 128;
  const int bn = blockIdx.y * 128;
  const int wm = (w & 1) * 64;
  const int wn = (w >> 1) * 64;
  const int lm = lane & 15;
  const int lc = lane >> 4;  // 0..3

  f32x4 acc[4][4] = {};

  // staging: thread -> (row srow = tid>>3, phys chunk p = tid&7)
  // content at (row,p) = logical chunk p ^ (row&7).
  const int srow = tid >> 3;
  const int swz = ((tid & 7) ^ (srow & 7)) * 8;
  const bf16_t* gA = A + (size_t)(bm + srow) * DIM + swz;
  const bf16_t* gW = W + (size_t)(bn + srow) * DIM + swz;
  char* lA = (char*)sA + w * 1024;  // wave-uniform base (lane*16 implied)
  char* lB = (char*)sB + w * 1024;

  for (int kt = 0; kt < DIM; kt += 64) {
#pragma unroll
    for (int q = 0; q < 4; ++q) {
      gload16(gA + kt + (size_t)q * 32 * DIM, lA + q * 4096);
      gload16(gW + kt + (size_t)q * 32 * DIM, lB + q * 4096);
    }
    __syncthreads();  // drain staging
#pragma unroll
    for (int kh = 0; kh < 2; ++kh) {
      bf16x8 aF[4], bF[4];
      const int lgc = kh * 4 + lc;
#pragma unroll
      for (int i = 0; i < 4; ++i) {
        const int rowA = wm + i * 16 + lm;
        aF[i] = *(const bf16x8*)((char*)sA + rowA * 128 +
                                 ((lgc ^ (lm & 7)) << 4));
      }
#pragma unroll
      for (int j = 0; j < 4; ++j) {
        const int rowB = wn + j * 16 + lm;
        bF[j] = *(const bf16x8*)((char*)sB + rowB * 128 +
                                 ((lgc ^ (lm & 7)) << 4));
      }
#pragma unroll
      for (int i = 0; i < 4; ++i)
#pragma unroll
        for (int j = 0; j < 4; ++j)
          acc[i][j] = __builtin_amdgcn_mfma_f32_16x16x32_bf16(
              aF[i], bF[j], acc[i][j], 0, 0, 0);
    }
    __syncthreads();  // protect LDS before next stage
  }

  // C/D layout: col = lane&15, row = (lane>>4)*4 + reg  [m89/m91]
  const int r0 = lc << 2;
#pragma unroll
  for (int i = 0; i < 4; ++i) {
    const int rowBase = bm + wm + i * 16 + r0;
    if constexpr (MODE == 0) {
      float s4[4];
#pragma unroll
      for (int r = 0; r < 4; ++r) s4[r] = scaleArr[rowBase + r];
#pragma unroll
      for (int j = 0; j < 4; ++j) {
        const int col = bn + wn + j * 16 + lm;
        const float bv = bias[col];
#pragma unroll
        for (int r = 0; r < 4; ++r)
          outB[(size_t)(rowBase + r) * DIM + col] =
              (bf16_t)fast_tanh(s4[r] * acc[i][j][r] + bv);
      }
    } else {
      f32x4 cf[4];
#pragma unroll
      for (int r = 0; r < 4; ++r) cf[r] = coef[rowBase + r];
#pragma unroll
      for (int j = 0; j < 4; ++j) {
        const int col = bn + wn + j * 16 + lm;
        const f32x4 cp = colpack[col];  // {e, c, n, b2}
#pragma unroll
        for (int r = 0; r < 4; ++r) {
          const size_t idx = (size_t)(rowBase + r) * DIM + col;
          const float hp = (float)hbIn[idx];
          const float v = acc[i][j][r] + cp.w + cf[r].x * cp.x +
                          cf[r].y * cp.y + cf[r].z * cp.z + cf[r].w * hp;
          outB[idx] = (bf16_t)v;
          if constexpr (MODE == 2) outF[idx] = v;
        }
      }
    }
  }
}

// ---------------------------------------------------------------------------
// Per-row stats: ||h||^2 and dots with e/c/n; produce
//   scaleArr[row] = clamp scale; coef[row] = {ce, cc, cn, scale*(1-ce-cc-cn)}
// IN_FP32: src fp32 (layer 0; also casts to hb). Else bf16.
// ---------------------------------------------------------------------------
template <int IN_FP32>
__global__ __launch_bounds__(256) void stats_kernel(
    const void* __restrict__ src, bf16_t* __restrict__ dstb,
    float* __restrict__ scaleArr, f32x4* __restrict__ coef,
    const float* __restrict__ dirs, int doClamp) {
  const int row = blockIdx.x;
  const int t = threadIdx.x;
  float4 v;
  if constexpr (IN_FP32) {
    v = ((const float4*)src)[(size_t)row * 256 + t];
  } else {
    const ushort4 u = ((const ushort4*)src)[(size_t)row * 256 + t];
    v.x = bf2f(u.x); v.y = bf2f(u.y); v.z = bf2f(u.z); v.w = bf2f(u.w);
  }
  const float4 e = ((const float4*)dirs)[t];
  const float4 c = ((const float4*)dirs)[t + 256];
  const float4 n = ((const float4*)dirs)[t + 512];
  float ss = v.x * v.x + v.y * v.y + v.z * v.z + v.w * v.w;
  float de = v.x * e.x + v.y * e.y + v.z * e.z + v.w * e.w;
  float dc = v.x * c.x + v.y * c.y + v.z * c.z + v.w * c.w;
  float dn = v.x * n.x + v.y * n.y + v.z * n.z + v.w * n.w;
#pragma unroll
  for (int off = 32; off; off >>= 1) {
    ss += __shfl_down(ss, off);
    de += __shfl_down(de, off);
    dc += __shfl_down(dc, off);
    dn += __shfl_down(dn, off);
  }
  __shared__ float red[4][4];
  const int w = t >> 6;
  if ((t & 63) == 0) {
    red[w][0] = ss; red[w][1] = de; red[w][2] = dc; red[w][3] = dn;
  }
  __syncthreads();
  if constexpr (IN_FP32) {
    union { bf16_t b[4]; uint2 u; } pk;
    pk.b[0] = (bf16_t)v.x; pk.b[1] = (bf16_t)v.y;
    pk.b[2] = (bf16_t)v.z; pk.b[3] = (bf16_t)v.w;
    ((uint2*)dstb)[(size_t)row * 256 + t] = pk.u;
  }
  if (t == 0) {
    float S = 0, E = 0, C = 0, N = 0;
#pragma unroll
    for (int i = 0; i < 4; ++i) {
      S += red[i][0]; E += red[i][1]; C += red[i][2]; N += red[i][3];
    }
    const float norm = sqrtf(S);
    float scale = 1.f;
    if (doClamp && norm > 10.f) scale = 10.f / (norm + 1e-8f);
    const float invn = 1.f / fmaxf(norm, 1e-12f);
    const float ae = E * invn;
    const float ac = C * invn;
    const float an = N * invn;
    const float nc = norm * scale;
    const float re = sqrtf(fmaxf(nc * nc - 2.f * nc * ae + 1.f, 0.f));
    const float rc = sqrtf(fmaxf(nc * nc - 2.f * nc * ac + 1.f, 0.f));
    const float rn = sqrtf(fmaxf(nc * nc - 2.f * nc * an + 1.f, 0.f));
    const float boundary = fminf(fmaxf(1.f - fabsf(ae - ac), 0.f), 1.f);
    f32x4 cf;
    cf.x = 0.1f * (1.f - ae) / fmaxf(re, 1e-12f);
    cf.y = 0.1f * (1.f - ac) / fmaxf(rc, 1e-12f);
    cf.z = (0.05f * (1.f - an) + 0.05f * boundary) / fmaxf(rn, 1e-12f);
    cf.w = scale * (1.f - cf.x - cf.y - cf.z);
    coef[row] = cf;
    scaleArr[row] = scale;
  }
}

__global__ __launch_bounds__(256) void finalize_kernel(
    float* __restrict__ outF, const float* __restrict__ scaleArr) {
  const int row = blockIdx.x;
  const int t = threadIdx.x;
  const float s = scaleArr[row];
  float4 v = ((float4*)outF)[(size_t)row * 256 + t];
  v.x *= s; v.y *= s; v.z *= s; v.w *= s;
  ((float4*)outF)[(size_t)row * 256 + t] = v;
}

// Normalize anchors -> dirs[3*DIM]
__global__ __launch_bounds__(256) void prep_dirs(
    const float* __restrict__ ae, const float* __restrict__ ac,
    const float* __restrict__ an, float* __restrict__ dirs) {
  const int t = threadIdx.x;
  const float4 a = ((const float4*)ae)[t];
  const float4 b = ((const float4*)ac)[t];
  const float4 c = ((const float4*)an)[t];
  float sa = a.x * a.x + a.y * a.y + a.z * a.z + a.w * a.w;
  float sb = b.x * b.x + b.y * b.y + b.z * b.z + b.w * b.w;
  float sc = c.x * c.x + c.y * c.y + c.z * c.z + c.w * c.w;
#pragma unroll
  for (int off = 32; off; off >>= 1) {
    sa += __shfl_down(sa, off);
    sb += __shfl_down(sb, off);
    sc += __shfl_down(sc, off);
  }
  __shared__ float red[4][3];
  __shared__ float fin[3];
  const int w = t >> 6;
  if ((t & 63) == 0) { red[w][0] = sa; red[w][1] = sb; red[w][2] = sc; }
  __syncthreads();
  if (t == 0) {
    float x = 0, y = 0, z = 0;
#pragma unroll
    for (int i = 0; i < 4; ++i) { x += red[i][0]; y += red[i][1]; z += red[i][2]; }
    fin[0] = x; fin[1] = y; fin[2] = z;
  }
  __syncthreads();
  const float ia = 1.f / fmaxf(sqrtf(fin[0]), 1e-12f);
  const float ib = 1.f / fmaxf(sqrtf(fin[1]), 1e-12f);
  const float ic = 1.f / fmaxf(sqrtf(fin[2]), 1e-12f);
  float4 oa, ob, oc;
  oa.x = a.x * ia; oa.y = a.y * ia; oa.z = a.z * ia; oa.w = a.w * ia;
  ob.x = b.x * ib; ob.y = b.y * ib; ob.z = b.z * ib; ob.w = b.w * ib;
  oc.x = c.x * ic; oc.y = c.y * ic; oc.z = c.z * ic; oc.w = c.w * ic;
  ((float4*)dirs)[t] = oa;
  ((float4*)dirs)[t + 256] = ob;
  ((float4*)dirs)[t + 512] = oc;
}

// Build colpack[col] = {e[col], c[col], n[col], b2[col]}
__global__ __launch_bounds__(256) void prep_cols(
    const float* __restrict__ dirs, const float* __restrict__ b2,
    f32x4* __restrict__ colpack) {
  const int t = threadIdx.x;  // handles cols 4t..4t+3
  const float4 e = ((const float4*)dirs)[t];
  const float4 c = ((const float4*)dirs)[t + 256];
  const float4 n = ((const float4*)dirs)[t + 512];
  const float4 b = ((const float4*)b2)[t];
  f32x4 o;
  o.x = e.x; o.y = c.x; o.z = n.x; o.w = b.x; colpack[4 * t + 0] = o;
  o.x = e.y; o.y = c.y; o.z = n.y; o.w = b.y; colpack[4 * t + 1] = o;
  o.x = e.z; o.y = c.z; o.z = n.z; o.w = b.z; colpack[4 * t + 2] = o;
  o.x = e.w; o.y = c.w; o.z = n.w; o.w = b.w; colpack[4 * t + 3] = o;
}

__global__ __launch_bounds__(256) void cast_w_kernel(
    const float* __restrict__ W, bf16_t* __restrict__ Wb) {
  const int i = blockIdx.x * 256 + threadIdx.x;
  const float4 v = ((const float4*)W)[i];
  union { bf16_t b[4]; uint2 u; } pk;
  pk.b[0] = (bf16_t)v.x; pk.b[1] = (bf16_t)v.y;
  pk.b[2] = (bf16_t)v.z; pk.b[3] = (bf16_t)v.w;
  ((uint2*)Wb)[i] = pk.u;
}

extern "C" void kernel_launch(void* const* d_in, const int* in_sizes, int n_in,
                              void* d_out, int out_size, void* d_ws,
                              size_t ws_size, hipStream_t stream) {
  const float* h0 = (const float*)d_in[0];
  const float* W1 = (const float*)d_in[1];
  const float* b1 = (const float*)d_in[2];
  const float* W2 = (const float*)d_in[3];
  const float* b2 = (const float*)d_in[4];
  const float* ae = (const float*)d_in[5];
  const float* ac = (const float*)d_in[6];
  const float* an = (const float*)d_in[7];
  float* outF = (float*)d_out;

  char* ws = (char*)d_ws;
  bf16_t* hb = (bf16_t*)ws;  ws += (size_t)BATCH * DIM * 2;   // 32 MB
  bf16_t* Tb = (bf16_t*)ws;  ws += (size_t)BATCH * DIM * 2;   // 32 MB
  bf16_t* W1b = (bf16_t*)ws; ws += (size_t)DIM * DIM * 2;     // 2 MB
  bf16_t* W2b = (bf16_t*)ws; ws += (size_t)DIM * DIM * 2;     // 2 MB
  float* dirs = (float*)ws;  ws += 3 * DIM * 4;
  f32x4* colpack = (f32x4*)ws; ws += DIM * 16;
  f32x4* coef = (f32x4*)ws;  ws += (size_t)BATCH * 16;
  float* scaleArr = (float*)ws; ws += (size_t)BATCH * 4;

  prep_dirs<<<1, 256, 0, stream>>>(ae, ac, an, dirs);
  prep_cols<<<1, 256, 0, stream>>>(dirs, b2, colpack);
  cast_w_kernel<<<DIM * DIM / 1024, 256, 0, stream>>>(W1, W1b);
  cast_w_kernel<<<DIM * DIM / 1024, 256, 0, stream>>>(W2, W2b);
  stats_kernel<1><<<BATCH, 256, 0, stream>>>(h0, hb, scaleArr, coef, dirs, 0);

  dim3 grid(BATCH / 128, DIM / 128);
  for (int l = 0; l < NLAYER; ++l) {
    gemm_kernel<0><<<grid, 256, 0, stream>>>(hb, W1b, b1, Tb, nullptr, nullptr,
                                             nullptr, scaleArr, nullptr);
    if (l < NLAYER - 1) {
      gemm_kernel<1><<<grid, 256, 0, stream>>>(Tb, W2b, b2, hb, nullptr, coef,
                                               colpack, nullptr, hb);
      stats_kernel<0><<<BATCH, 256, 0, stream>>>(hb, nullptr, scaleArr, coef,
                                                 dirs, 1);
    } else {
      gemm_kernel<2><<<grid, 256, 0, stream>>>(Tb, W2b, b2, hb, outF, coef,
                                               colpack, nullptr, hb);
      stats_kernel<0><<<BATCH, 256, 0, stream>>>(hb, nullptr, scaleArr, coef,
                                                 dirs, 1);
      finalize_kernel<<<BATCH, 256, 0, stream>>>(outF, scaleArr);
    }
  }
}